// Round 4
// baseline (4039.532 us; speedup 1.0000x reference)
//
#include <hip/hip_runtime.h>

typedef __attribute__((ext_vector_type(8))) short short8;
typedef __attribute__((ext_vector_type(4))) float floatx4;
typedef unsigned short u16;
typedef __attribute__((ext_vector_type(4))) unsigned short u16x4;
typedef unsigned long long u64;

#define B_ 128
#define S_ 512
#define D_ 256
#define H_ 512
#define O_ 256

__device__ __forceinline__ u16 f2bf(float f) {
  union { float f; unsigned u; } v; v.f = f;
  unsigned r = v.u + 0x7fffu + ((v.u >> 16) & 1u);
  return (u16)(r >> 16);
}
__device__ __forceinline__ float sigf(float x) { return 1.f / (1.f + __expf(-x)); }
__device__ __forceinline__ float tanhf_fast(float x) { return 1.f - 2.f / (__expf(2.f * x) + 1.f); }

// 8B load bypassing L1/L2 (device-coherent, served by the MALL).
// RELAXED+AGENT atomics emit flagged loads with NO cache-maintenance fences.
__device__ __forceinline__ u64 ld_u64_agent(const u64* p) {
  return __hip_atomic_load(p, __ATOMIC_RELAXED, __HIP_MEMORY_SCOPE_AGENT);
}

// ---------------- conversion kernels ----------------
__global__ __launch_bounds__(256) void cvt_bf16_vec(const float* __restrict__ in,
                                                    u16* __restrict__ out, int n4) {
  int i = blockIdx.x * 256 + threadIdx.x;
  if (i < n4) {
    const float4 v = ((const float4*)in)[i];
    u16x4 o;
    o.x = f2bf(v.x); o.y = f2bf(v.y); o.z = f2bf(v.z); o.w = f2bf(v.w);
    ((u16x4*)out)[i] = o;
  }
}

// out[c][r] = in[r][c]; in is [R][C] f32, out is [C][R] bf16
__global__ __launch_bounds__(256) void transpose_cvt(const float* __restrict__ in,
                                                     u16* __restrict__ out, int R, int C) {
  int idx = blockIdx.x * 256 + threadIdx.x;
  if (idx < R * C) {
    int r = idx % R, c = idx / R;
    out[idx] = f2bf(in[(size_t)r * C + c]);
  }
}

// ---------------- persistent scan kernel ----------------
// grid = 256 WGs x 320 threads (5 waves).  g = blockIdx&7 (XCD swizzle),
// mem = blockIdx>>3 -> units [16*mem, 16*mem+16).  Each WG serves TWO
// independent 8-batch contexts: A = batches [16g,16g+8), B = [16g+8,16g+16),
// each with its own 32-WG barrier (counters 2g / 2g+1).  Per step the WG
// alternates halves; context X's MALL latencies (release poll, slab load,
// store drain) overlap context Y's compute.  MFMA uses M=16 with 8 valid
// rows (row addr clamped lm&7).  Exchange (h,c bf16) via RELAXED agent-scope
// atomics (MALL-coherent, no L2 sweeps).
#define PU 520   // padded K-stride for K=512 tiles (2-way bank alias: free)
#define PX 264   // padded K-stride for K=256 tiles
#define SCAN_SMEM ((size_t)(4*16*PU + 4*16*PX + 3*16*PU) * 2 + (size_t)5*272*4)

#define MFMA_BF16 __builtin_amdgcn_mfma_f32_16x16x32_bf16

// One pipelined half-step: compute context X at step SX; wait/load context Y's
// slab for step SY.  All names from enclosing scope.
#define HALF_STEP(SX, SY, B0X, B0Y, LHX, LCX, LHY, LCY, PXAX, PXAY, CREGX, BARX, BARY) { \
    /* ---- compute X: x-chain + h/c dual chains ---- */                               \
    floatx4 accx = {0.f,0.f,0.f,0.f}, a0 = {0.f,0.f,0.f,0.f}, a1 = {0.f,0.f,0.f,0.f}; \
    if (wv < 4) {                                                                      \
      const u16* bX = ldsX + (wv * 16 + lm) * PX + quad * 8;                           \
      _Pragma("unroll")                                                                \
      for (int it = 0; it < 8; ++it)                                                   \
        accx = MFMA_BF16(PXAX[it], *(const short8*)(bX + it * 32), accx, 0, 0, 0);     \
      const u16* arow = LHX + (lm & 7) * PU + quad * 8;                                \
      const u16* bU = ldsU + (wv * 16 + lm) * PU + quad * 8;                           \
      _Pragma("unroll")                                                                \
      for (int it = 0; it < 8; ++it) {                                                 \
        a0 = MFMA_BF16(*(const short8*)(arow + it * 32),                               \
                       *(const short8*)(bU + it * 32), a0, 0, 0, 0);                   \
        a1 = MFMA_BF16(*(const short8*)(arow + (it + 8) * 32),                         \
                       *(const short8*)(bU + (it + 8) * 32), a1, 0, 0, 0);             \
      }                                                                                \
    } else {                                                                           \
      const u16* arow = LCX + (lm & 7) * PU + quad * 8;                                \
      const u16* bC = ldsC + lm * PU + quad * 8;                                       \
      _Pragma("unroll")                                                                \
      for (int it = 0; it < 8; ++it) {                                                 \
        a0 = MFMA_BF16(*(const short8*)(arow + it * 32),                               \
                       *(const short8*)(bC + it * 32), a0, 0, 0, 0);                   \
        a1 = MFMA_BF16(*(const short8*)(arow + (it + 8) * 32),                         \
                       *(const short8*)(bC + (it + 8) * 32), a1, 0, 0, 0);             \
      }                                                                                \
    }                                                                                  \
    { float* P = ldsP + wv * 272;                                                      \
      _Pragma("unroll")                                                                \
      for (int r = 0; r < 4; ++r)                                                      \
        P[(quad * 4 + r) * 17 + lm] = accx[r] + a0[r] + a1[r]; }                       \
    /* ---- wait Y's producers (usually already released) ---- */                      \
    if (tid == 0) {                                                                    \
      const unsigned tgt = 32u * (unsigned)(SY);                                       \
      while (__hip_atomic_load(BARY, __ATOMIC_RELAXED, __HIP_MEMORY_SCOPE_AGENT) < tgt)\
        __builtin_amdgcn_s_sleep(1);                                                   \
    }                                                                                  \
    __syncthreads();   /* P visible + Y-slab released */                               \
    /* ---- issue Y slab loads (regs) ---- */                                          \
    u64 hq[8];                                                                         \
    if (tid < 256) {                                                                   \
      const int sb = (SY) & 1;                                                         \
      const u64* hsrc = (const u64*)(h_state + (size_t)sb * B_ * H_) + (size_t)(B0Y) * 128; \
      const u64* csrc = (const u64*)(c_state + (size_t)sb * B_ * H_) + (size_t)(B0Y) * 128; \
      _Pragma("unroll")                                                                \
      for (int k = 0; k < 8; ++k) {                                                    \
        const int qq = tid + 256 * (k & 3);                                            \
        hq[k] = ld_u64_agent(((k < 4) ? hsrc : csrc) + qq);                            \
      }                                                                                \
    }                                                                                  \
    /* ---- prefetch Y x-fragments ---- */                                             \
    if (wv < 4) {                                                                      \
      const int sn = (SY) < S_ ? (SY) : S_ - 1;                                        \
      const u16* xrow = xbf + ((size_t)((B0Y) + (lm & 7)) * S_ + sn) * D_ + quad * 8;  \
      _Pragma("unroll")                                                                \
      for (int it = 0; it < 8; ++it) PXAX##_dummy: ;                                   \
    }                                                                                  \
  }

// (HALF_STEP is finished inline below; macro kept readable by splitting —
//  see half_step usage in the kernel body.)

__global__ __launch_bounds__(320, 1) void tlstm_scan(
    const u16* __restrict__ xbf,      // [B,S,D] bf16
    const float* __restrict__ tdiff,  // [B,S]
    const u16* __restrict__ UallT,    // [4H][H]  bf16 (B^T layout)
    const u16* __restrict__ WallT,    // [4H][D]
    const u16* __restrict__ WdT,      // [H][H]
    const float* __restrict__ b_all, const float* __restrict__ b_u,
    const float* __restrict__ b_d,
    u16* __restrict__ h_state,        // [2][B][H] bf16 ping-pong (exchange)
    u16* __restrict__ c_state,        // [2][B][H] bf16 ping-pong (exchange)
    unsigned* __restrict__ bar,       // 16 counters, 256B apart
    float* __restrict__ d_hs, float* __restrict__ d_cs,
    u16* __restrict__ hs_bf)          // [B,S,H] bf16 (gemm2 input)
{
  extern __shared__ char smem[];
  u16* ldsU  = (u16*)smem;                 // [64][PU]
  u16* ldsX  = ldsU + 64 * PU;             // [64][PX]
  u16* ldsC  = ldsX + 64 * PX;             // [16][PU]  W_d slice
  u16* ldsHA = ldsC + 16 * PU;             // [8][PU]   context A h slab
  u16* ldsCA = ldsHA + 8 * PU;             // [8][PU]   context A c slab
  u16* ldsHB = ldsCA + 8 * PU;             // [8][PU]   context B h slab
  u16* ldsCB = ldsHB + 8 * PU;             // [8][PU]   context B c slab
  float* ldsP = (float*)(ldsCB + 8 * PU);  // [5][272]

  const int g = blockIdx.x & 7, mem = blockIdx.x >> 3;
  const int U0 = mem * 16;
  const int B0A = g * 16, B0B = g * 16 + 8;
  unsigned* barA = bar + (2 * g) * 64;
  unsigned* barB = bar + (2 * g + 1) * 64;
  const int tid = threadIdx.x;

  // ---- stage weight slices into LDS (once) ----
  for (int i = tid; i < 4 * 16 * 64; i += 320) {       // U tiles
    int w = i >> 10, r = i & 1023, n = r >> 6, kb = r & 63;
    *(short8*)(ldsU + (w * 16 + n) * PU + kb * 8) =
        *(const short8*)(UallT + (size_t)(w * 512 + U0 + n) * 512 + kb * 8);
  }
  for (int i = tid; i < 4 * 16 * 32; i += 320) {       // W_all tiles
    int w = i >> 9, r = i & 511, n = r >> 5, kb = r & 31;
    *(short8*)(ldsX + (w * 16 + n) * PX + kb * 8) =
        *(const short8*)(WallT + (size_t)(w * 512 + U0 + n) * 256 + kb * 8);
  }
  for (int i = tid; i < 16 * 64; i += 320) {           // W_d tile
    int n = i >> 6, kb = i & 63;
    *(short8*)(ldsC + n * PU + kb * 8) =
        *(const short8*)(WdT + (size_t)(U0 + n) * 512 + kb * 8);
  }
  // zero context-A slabs for step 0 (initial state = 0)
  for (int i = tid; i < 8 * 512; i += 320) {
    const int row = i >> 9, col = i & 511;
    ldsHA[row * PU + col] = 0;
    ldsCA[row * PU + col] = 0;
  }

  // ---- per-thread elementwise constants (used by tid<128) ----
  const int em = tid >> 4, eu = tid & 15;
  const int ug = U0 + eu;
  float bf_ = 0.f, bi_ = 0.f, bo_ = 0.f, bg_ = 0.f, bd_ = 0.f;
  if (tid < 256) {
    bf_ = b_all[ug] + b_u[ug];
    bi_ = b_all[512 + ug] + b_u[512 + ug];
    bo_ = b_all[1024 + ug] + b_u[1024 + ug];
    bg_ = b_all[1536 + ug] + b_u[1536 + ug];
    bd_ = b_d[ug];
  }
  const int wv = tid >> 6, lane = tid & 63, lm = lane & 15, quad = lane >> 4;
  float cregA = 0.f, cregB = 0.f;

  // prefetch context-A x fragments for step 0
  short8 pxaA[8], pxaB[8];
  if (wv < 4) {
    const u16* xrow = xbf + (size_t)(B0A + (lm & 7)) * S_ * D_ + quad * 8;
#pragma unroll
    for (int it = 0; it < 8; ++it) pxaA[it] = *(const short8*)(xrow + it * 32);
  }
  __syncthreads();

#define HALF(SX, SY, B0X, B0Y, LHX, LCX, LHY, LCY, PXA_X, PXA_Y, CREGX, BARX, BARY)    \
  {                                                                                    \
    floatx4 accx = {0.f,0.f,0.f,0.f}, a0 = {0.f,0.f,0.f,0.f}, a1 = {0.f,0.f,0.f,0.f}; \
    if (wv < 4) {                                                                      \
      const u16* bXp = ldsX + (wv * 16 + lm) * PX + quad * 8;                          \
      _Pragma("unroll")                                                                \
      for (int it = 0; it < 8; ++it)                                                   \
        accx = MFMA_BF16(PXA_X[it], *(const short8*)(bXp + it * 32), accx, 0, 0, 0);   \
      const u16* arow = LHX + (lm & 7) * PU + quad * 8;                                \
      const u16* bU = ldsU + (wv * 16 + lm) * PU + quad * 8;                           \
      _Pragma("unroll")                                                                \
      for (int it = 0; it < 8; ++it) {                                                 \
        a0 = MFMA_BF16(*(const short8*)(arow + it * 32),                               \
                       *(const short8*)(bU + it * 32), a0, 0, 0, 0);                   \
        a1 = MFMA_BF16(*(const short8*)(arow + (it + 8) * 32),                         \
                       *(const short8*)(bU + (it + 8) * 32), a1, 0, 0, 0);             \
      }                                                                                \
    } else {                                                                           \
      const u16* arow = LCX + (lm & 7) * PU + quad * 8;                                \
      const u16* bC = ldsC + lm * PU + quad * 8;                                       \
      _Pragma("unroll")                                                                \
      for (int it = 0; it < 8; ++it) {                                                 \
        a0 = MFMA_BF16(*(const short8*)(arow + it * 32),                               \
                       *(const short8*)(bC + it * 32), a0, 0, 0, 0);                   \
        a1 = MFMA_BF16(*(const short8*)(arow + (it + 8) * 32),                         \
                       *(const short8*)(bC + (it + 8) * 32), a1, 0, 0, 0);             \
      }                                                                                \
    }                                                                                  \
    { float* P = ldsP + wv * 272;                                                      \
      _Pragma("unroll")                                                                \
      for (int r = 0; r < 4; ++r)                                                      \
        P[(quad * 4 + r) * 17 + lm] = accx[r] + a0[r] + a1[r]; }                       \
    if (tid == 0) {                                                                    \
      const unsigned tgt = 32u * (unsigned)(SY);                                       \
      while (__hip_atomic_load(BARY, __ATOMIC_RELAXED, __HIP_MEMORY_SCOPE_AGENT) < tgt)\
        __builtin_amdgcn_s_sleep(1);                                                   \
    }                                                                                  \
    __syncthreads();                                                                   \
    u64 hq[8];                                                                         \
    if (tid < 256) {                                                                   \
      const int sb = (SY) & 1;                                                         \
      const u64* hsrc = (const u64*)(h_state + (size_t)sb * B_ * H_) + (size_t)(B0Y) * 128; \
      const u64* csrc = (const u64*)(c_state + (size_t)sb * B_ * H_) + (size_t)(B0Y) * 128; \
      _Pragma("unroll")                                                                \
      for (int k = 0; k < 8; ++k) {                                                    \
        const int qq = tid + 256 * (k & 3);                                            \
        hq[k] = ld_u64_agent(((k < 4) ? hsrc : csrc) + qq);                            \
      }                                                                                \
    }                                                                                  \
    if (wv < 4) {                                                                      \
      const int sn = (SY) < S_ ? (SY) : S_ - 1;                                        \
      const u16* xrow = xbf + ((size_t)((B0Y) + (lm & 7)) * S_ + sn) * D_ + quad * 8;  \
      _Pragma("unroll")                                                                \
      for (int it = 0; it < 8; ++it) PXA_Y[it] = *(const short8*)(xrow + it * 32);     \
    }                                                                                  \
    float ht_s = 0.f, ct_s = 0.f; unsigned hb_s = 0; size_t oidx = 0;                  \
    if (tid < 128) {                                                                   \
      const int ebb = (B0X) + em;                                                      \
      const float f   = ldsP[0 * 272 + em * 17 + eu];                                  \
      const float ii  = ldsP[1 * 272 + em * 17 + eu];                                  \
      const float oo  = ldsP[2 * 272 + em * 17 + eu];                                  \
      const float ggv = ldsP[3 * 272 + em * 17 + eu];                                  \
      const float csp = ldsP[4 * 272 + em * 17 + eu];                                  \
      const float tt = tdiff[(size_t)ebb * S_ + (SX)];                                 \
      const float cst = sigf(csp + bd_);                                               \
      const float cadj = CREGX - cst + cst * tt;                                       \
      const float fv = sigf(f + bf_), iv = sigf(ii + bi_), ov = sigf(oo + bo_);        \
      const float gv = tanhf_fast(ggv + bg_);                                          \
      const float ct = fv * cadj + iv * gv;                                            \
      const float ht = ov * tanhf_fast(ct);                                            \
      CREGX = ct; ht_s = ht; ct_s = ct;                                                \
      oidx = ((size_t)ebb * S_ + (SX)) * H_ + ug;                                      \
      const unsigned hb = (unsigned)f2bf(ht);                                          \
      const unsigned cb = (unsigned)f2bf(ct);                                          \
      hb_s = hb;                                                                       \
      const unsigned hn = (unsigned)__shfl_xor((int)hb, 1);                            \
      const unsigned cn = (unsigned)__shfl_xor((int)cb, 1);                            \
      if (!(eu & 1)) {                                                                 \
        u16* hnxt = h_state + (size_t)(((SX) + 1) & 1) * B_ * H_;                      \
        u16* cnxt = c_state + (size_t)(((SX) + 1) & 1) * B_ * H_;                      \
        const size_t wi = ((size_t)ebb * H_ + ug) >> 1;                                \
        __hip_atomic_store((unsigned*)hnxt + wi, hb | (hn << 16),                      \
                           __ATOMIC_RELAXED, __HIP_MEMORY_SCOPE_AGENT);                \
        __hip_atomic_store((unsigned*)cnxt + wi, cb | (cn << 16),                      \
                           __ATOMIC_RELAXED, __HIP_MEMORY_SCOPE_AGENT);                \
      }                                                                                \
    }                                                                                  \
    __syncthreads();   /* drains exchange stores (and slab loads) */                   \
    if (tid == 0)                                                                      \
      __hip_atomic_fetch_add(BARX, 1u, __ATOMIC_RELAXED, __HIP_MEMORY_SCOPE_AGENT);    \
    if (tid < 128) {   /* deferred HBM output stores, drain off critical path */       \
      d_hs[oidx] = ht_s; d_cs[oidx] = ct_s; hs_bf[oidx] = (u16)hb_s;                   \
    }                                                                                  \
    if (tid < 256) {                                                                   \
      _Pragma("unroll")                                                                \
      for (int k = 0; k < 8; ++k) {                                                    \
        const int qq = tid + 256 * (k & 3);                                            \
        const int row = qq >> 7, c8 = qq & 127;                                        \
        *(u64*)(((k < 4) ? LHY : LCY) + row * PU + c8 * 4) = hq[k];                    \
      }                                                                                \
    }                                                                                  \
    __syncthreads();                                                                   \
  }

  for (int s = 0; s < S_; ++s) {
    HALF(s, s,     B0A, B0B, ldsHA, ldsCA, ldsHB, ldsCB, pxaA, pxaB, cregA, barA, barB)
    HALF(s, s + 1, B0B, B0A, ldsHB, ldsCB, ldsHA, ldsCA, pxaB, pxaA, cregB, barB, barA)
  }
#undef HALF
}

// ---------------- output GEMM: out = hs_bf16 @ W_out + b_out ----------------
// M=65536, N=256, K=512.  WG 256 thr = 2x2 waves, each wave 32x32.
__global__ __launch_bounds__(256, 4) void gemm2(const u16* __restrict__ A,
                                                const u16* __restrict__ Bt,
                                                const float* __restrict__ bias,
                                                float* __restrict__ C) {
  const int K = 512, N = 256;
  const int wave = threadIdx.x >> 6, lane = threadIdx.x & 63;
  const int wm = wave >> 1, wn = wave & 1;
  const int lm = lane & 15, quad = lane >> 4;
  const int Mb = blockIdx.x * 64 + wm * 32;
  const int Nb = blockIdx.y * 64 + wn * 32;
  const u16* a0 = A + (size_t)(Mb + lm) * K + quad * 8;
  const u16* a1 = a0 + (size_t)16 * K;
  const u16* b0 = Bt + (size_t)(Nb + lm) * K + quad * 8;
  const u16* b1 = b0 + (size_t)16 * K;
  floatx4 acc00 = {0,0,0,0}, acc01 = {0,0,0,0}, acc10 = {0,0,0,0}, acc11 = {0,0,0,0};
#pragma unroll 4
  for (int k = 0; k < K; k += 32) {
    short8 av0 = *(const short8*)(a0 + k);
    short8 av1 = *(const short8*)(a1 + k);
    short8 bv0 = *(const short8*)(b0 + k);
    short8 bv1 = *(const short8*)(b1 + k);
    acc00 = MFMA_BF16(av0, bv0, acc00, 0, 0, 0);
    acc01 = MFMA_BF16(av0, bv1, acc01, 0, 0, 0);
    acc10 = MFMA_BF16(av1, bv0, acc10, 0, 0, 0);
    acc11 = MFMA_BF16(av1, bv1, acc11, 0, 0, 0);
  }
  const float bia0 = bias[Nb + lm], bia1 = bias[Nb + 16 + lm];
#pragma unroll
  for (int r = 0; r < 4; ++r) {
    const int row0 = Mb + quad * 4 + r;
    C[(size_t)row0 * N + Nb + lm]            = acc00[r] + bia0;
    C[(size_t)row0 * N + Nb + 16 + lm]       = acc01[r] + bia1;
    C[(size_t)(row0 + 16) * N + Nb + lm]     = acc10[r] + bia0;
    C[(size_t)(row0 + 16) * N + Nb + 16 + lm] = acc11[r] + bia1;
  }
}

// ---------------- host ----------------
extern "C" void kernel_launch(void* const* d_in, const int* in_sizes, int n_in,
                              void* d_out, int out_size, void* d_ws, size_t ws_size,
                              hipStream_t stream) {
  const float* inputs = (const float*)d_in[0];
  const float* tdiff  = (const float*)d_in[1];
  // d_in[2] = seq_lens : unused by the reference
  const float* W_all = (const float*)d_in[3];
  const float* b_all = (const float*)d_in[4];
  const float* U_all = (const float*)d_in[5];
  const float* b_u   = (const float*)d_in[6];
  const float* W_d   = (const float*)d_in[7];
  const float* b_d   = (const float*)d_in[8];
  const float* W_out = (const float*)d_in[9];
  const float* b_out = (const float*)d_in[10];

  float* out = (float*)d_out;
  float* d_outputs = out;                                   // [B,S,O]
  float* d_hs = out + (size_t)B_ * S_ * O_;                 // [B,S,H]
  float* d_cs = d_hs + (size_t)B_ * S_ * H_;                // [B,S,H]

  char* ws = (char*)d_ws;
  size_t off = 0;
  auto alloc = [&](size_t bytes) {
    char* p = ws + off;
    off += (bytes + 255) & ~(size_t)255;
    return p;
  };
  u16* xbf      = (u16*)alloc((size_t)B_ * S_ * D_ * 2);        // 32 MB
  u16* hs_bf    = (u16*)alloc((size_t)B_ * S_ * H_ * 2);        // 64 MB
  u16* UallT    = (u16*)alloc((size_t)2048 * 512 * 2);
  u16* WallT    = (u16*)alloc((size_t)2048 * 256 * 2);
  u16* WdT      = (u16*)alloc((size_t)512 * 512 * 2);
  u16* WoutT    = (u16*)alloc((size_t)256 * 512 * 2);
  u16* h_state  = (u16*)alloc((size_t)2 * B_ * H_ * 2);
  u16* c_state  = (u16*)alloc((size_t)2 * B_ * H_ * 2);
  unsigned* bar = (unsigned*)alloc(4096);

  // zero initial state + barrier counters (ws is re-poisoned before every call)
  hipMemsetAsync(h_state, 0, (size_t)2 * B_ * H_ * 2, stream);
  hipMemsetAsync(c_state, 0, (size_t)2 * B_ * H_ * 2, stream);
  hipMemsetAsync(bar, 0, 4096, stream);

  cvt_bf16_vec<<<(B_ * S_ * D_ / 4 + 255) / 256, 256, 0, stream>>>(inputs, xbf, B_ * S_ * D_ / 4);
  transpose_cvt<<<(256 * 2048 + 255) / 256, 256, 0, stream>>>(W_all, WallT, 256, 2048);
  transpose_cvt<<<(512 * 2048 + 255) / 256, 256, 0, stream>>>(U_all, UallT, 512, 2048);
  transpose_cvt<<<(512 * 512 + 255) / 256, 256, 0, stream>>>(W_d, WdT, 512, 512);
  transpose_cvt<<<(512 * 256 + 255) / 256, 256, 0, stream>>>(W_out, WoutT, 512, 256);

  (void)hipFuncSetAttribute((const void*)tlstm_scan,
                            hipFuncAttributeMaxDynamicSharedMemorySize, (int)SCAN_SMEM);
  tlstm_scan<<<256, 320, SCAN_SMEM, stream>>>(xbf, tdiff, UallT, WallT, WdT,
                                              b_all, b_u, b_d, h_state, c_state,
                                              bar, d_hs, d_cs, hs_bf);
  gemm2<<<dim3(B_ * S_ / 64, O_ / 64), 256, 0, stream>>>(hs_bf, WoutT, b_out, d_outputs);
}